// Round 7
// baseline (1148.248 us; speedup 1.0000x reference)
//
#include <hip/hip_runtime.h>
#include <hip/hip_bf16.h>
#include <math.h>

// G2GDecoder forward: TreeGRU over line graph + topology/label heads.
// R2: CSR-gather segment sums. R5: bf16 MFMA.
// R7: register-resident W. Each block loads its W fragments into VGPRs once
// (one-time L2 read), then grid-strides over M-tiles with a barrier-free,
// LDS-free K-loop: stream A f32 from HBM -> cvt_pk bf16 -> MFMA. R6's
// latency problem (W L2 loads on the MFMA critical path at 22% occupancy)
// is removed entirely. GRU z/h~ fused at 16 cols/wave (both W mats in regs);
// msg_new written to a fresh buffer (fixes R6's in-place cross-wave race).

using bf16x8 = __attribute__((ext_vector_type(8))) short;
using f32x4  = __attribute__((ext_vector_type(4))) float;

__device__ inline float wave_sum64(float v){
  #pragma unroll
  for (int m = 32; m; m >>= 1) v += __shfl_xor(v, m, 64);
  return v;
}
__device__ inline float wave_max64(float v){
  #pragma unroll
  for (int m = 32; m; m >>= 1) v = fmaxf(v, __shfl_xor(v, m, 64));
  return v;
}
__device__ inline float sigmoidf_(float x){ return 1.f / (1.f + __expf(-x)); }
__device__ inline float tanh_fast(float x){
  x = fminf(fmaxf(x, -15.f), 15.f);
  float e = __expf(2.f * x);
  return (e - 1.f) / (e + 1.f);
}
__device__ inline float logsigf_(float x){
  return (x >= 0.f) ? -log1pf(__expf(-x)) : (x - log1pf(__expf(x)));
}
__device__ inline short f2bf(float f){
  union { float f; unsigned u; } v; v.f = f;
  const unsigned r = v.u + 0x7FFF + ((v.u >> 16) & 1);   // RNE
  return (short)(r >> 16);
}
__device__ inline unsigned pk2(short a, short b){
  return (unsigned)(unsigned short)a | ((unsigned)(unsigned short)b << 16);
}
// load 8 f32, convert to bf16x8 (compiler should emit v_cvt_pk_bf16_f32)
__device__ inline bf16x8 ldcvt(const float* __restrict__ p){
  const float4 x0 = *(const float4*)(p);
  const float4 x1 = *(const float4*)(p + 4);
  union { bf16x8 v; __hip_bfloat162 h[4]; } r;
  r.h[0] = __float22bfloat162_rn({x0.x, x0.y});
  r.h[1] = __float22bfloat162_rn({x0.z, x0.w});
  r.h[2] = __float22bfloat162_rn({x1.x, x1.y});
  r.h[3] = __float22bfloat162_rn({x1.z, x1.w});
  return r.v;
}

enum { EPI_NONE = 0, EPI_SIGMOID = 1, EPI_RELU = 2, EPI_SIGMUL = 3 };
enum { FM_PROJ2 = 0, FM_GRUMIX = 1 };

// ---------------- weight prep: f32 [k][col] -> bf16 fragment layout ----------
// granule g = k8*128 + col holds 8 bf16 (k = k8*8 .. +7) at wt[off + g*8].
__global__ __launch_bounds__(256) void wprep_kernel(
    const float* wr, const float* ur, const float* wz, const float* uz,
    const float* w,  const float* u,  const float* w_d1, const float* w_d2,
    const float* a_dT, const float* a_dG, const float* a_lT, const float* a_lG,
    const float* w_d3, const float* w_d4, const float* w_l1, const float* w_l2,
    short* __restrict__ wt)
{
  const int m = blockIdx.y;
  const float* s1; const float* s2; int K1, Ktot; size_t off;
  switch (m){
    case 0: s1 = wr;   s2 = ur;   K1 = 128; Ktot = 256; off = 0;      break;
    case 1: s1 = wz;   s2 = uz;   K1 = 128; Ktot = 256; off = 32768;  break;
    case 2: s1 = w;    s2 = u;    K1 = 128; Ktot = 256; off = 65536;  break;
    case 3: s1 = w_d1; s2 = w_d2; K1 = 128; Ktot = 256; off = 98304;  break;
    case 4: s1 = a_dT; s2 = nullptr; K1 = 128; Ktot = 128; off = 131072; break;
    case 5: s1 = a_dG; s2 = nullptr; K1 = 128; Ktot = 128; off = 147456; break;
    case 6: s1 = a_lT; s2 = nullptr; K1 = 128; Ktot = 128; off = 163840; break;
    case 7: s1 = a_lG; s2 = nullptr; K1 = 128; Ktot = 128; off = 180224; break;
    case 8: s1 = w_d3; s2 = w_d4; K1 = 128; Ktot = 384; off = 196608; break;
    default:s1 = w_l1; s2 = w_l2; K1 = 128; Ktot = 384; off = 245760; break;
  }
  const int tid = blockIdx.x * 256 + threadIdx.x;
  if (tid >= 16 * Ktot) return;
  const int col = tid & 127, k8 = tid >> 7;
  short v[8];
  #pragma unroll
  for (int i = 0; i < 8; ++i){
    const int k = k8 * 8 + i;
    const float* s = (k < K1) ? (s1 + (size_t)k * 128 + col)
                              : (s2 + (size_t)(k - K1) * 128 + col);
    v[i] = f2bf(*s);
  }
  uint4 pk;
  pk.x = pk2(v[0], v[1]); pk.y = pk2(v[2], v[3]);
  pk.z = pk2(v[4], v[5]); pk.w = pk2(v[6], v[7]);
  *(uint4*)&wt[off + ((size_t)k8 * 128 + col) * 8] = pk;
}

// ---------------- register-W MFMA GEMM (single output) ----------------
// C[M,128] = epi( A1[M,KS1*32]@W[0:..] + A2[M,KS2*32]@W[..:] + bias )
// 256 thr = 4 waves; wave owns 32 cols (2 frags) x 32 rows (2 frags).
// W fragments live in VGPRs for the whole kernel; grid-stride over M-tiles.
template<int KS1, int KS2, int EPI>
__global__ __launch_bounds__(256) void gemm_rw_kernel(
    int tiles,
    const float* __restrict__ A1, const float* __restrict__ A2,
    const short* __restrict__ Wt, const float* __restrict__ bias,
    const float* __restrict__ aux, float* __restrict__ out)
{
  const int t = threadIdx.x, wv = t >> 6, lane = t & 63;
  const int l15 = lane & 15, l4 = lane >> 4;
  constexpr int KS = KS1 + KS2;
  bf16x8 Wr[KS][2];
  #pragma unroll
  for (int ks = 0; ks < KS; ++ks)
    #pragma unroll
    for (int cf = 0; cf < 2; ++cf)
      Wr[ks][cf] = *(const bf16x8*)&Wt[((size_t)(ks * 4 + l4) * 128 + wv * 32 + cf * 16 + l15) * 8];

  for (int tile = blockIdx.x; tile < tiles; tile += gridDim.x){
    const int rw = tile * 32;
    f32x4 acc00 = {0.f,0.f,0.f,0.f}, acc01 = {0.f,0.f,0.f,0.f};
    f32x4 acc10 = {0.f,0.f,0.f,0.f}, acc11 = {0.f,0.f,0.f,0.f};
    #pragma unroll
    for (int ks = 0; ks < KS; ++ks){
      const float* A; int stride, kl;
      if (ks < KS1){ A = A1; stride = KS1 * 32; kl = ks * 32; }
      else         { A = A2; stride = KS2 * 32; kl = (ks - KS1) * 32; }
      kl += l4 * 8;
      const bf16x8 a0 = ldcvt(A + (size_t)(rw + l15) * stride + kl);
      const bf16x8 a1 = ldcvt(A + (size_t)(rw + 16 + l15) * stride + kl);
      acc00 = __builtin_amdgcn_mfma_f32_16x16x32_bf16(a0, Wr[ks][0], acc00, 0, 0, 0);
      acc01 = __builtin_amdgcn_mfma_f32_16x16x32_bf16(a0, Wr[ks][1], acc01, 0, 0, 0);
      acc10 = __builtin_amdgcn_mfma_f32_16x16x32_bf16(a1, Wr[ks][0], acc10, 0, 0, 0);
      acc11 = __builtin_amdgcn_mfma_f32_16x16x32_bf16(a1, Wr[ks][1], acc11, 0, 0, 0);
    }
    #pragma unroll
    for (int cf = 0; cf < 2; ++cf){
      const int col = wv * 32 + cf * 16 + l15;
      const float bv = bias ? bias[col] : 0.f;
      #pragma unroll
      for (int rf = 0; rf < 2; ++rf){
        const f32x4 ac = (rf == 0) ? (cf == 0 ? acc00 : acc01)
                                   : (cf == 0 ? acc10 : acc11);
        #pragma unroll
        for (int i = 0; i < 4; ++i){
          const int row = rw + rf * 16 + l4 * 4 + i;
          const size_t o = (size_t)row * 128 + col;
          float v = ac[i] + bv;
          if (EPI == EPI_SIGMOID)     v = sigmoidf_(v);
          else if (EPI == EPI_RELU)   v = fmaxf(v, 0.f);
          else if (EPI == EPI_SIGMUL) v = sigmoidf_(v) * aux[o];
          out[o] = v;
        }
      }
    }
  }
}

// ---------------- register-W MFMA GEMM (two mats / GRU or proj pair) -------
// acc1 = A1@W1[0:128] + A2@W1[128:], acc2 = A1@W2[0:128] + A3@W2[128:]
// FM_PROJ2 : out1 = acc1, out2 = acc2  (KS2 == 0)
// FM_GRUMIX: z = sig(acc1+b1), h = tanh(acc2+b2), out1 = (1-z)*aux + z*h
// 512 thr = 8 waves; wave owns 16 cols (1 frag) x 32 rows.
template<int KS2, int MODE>
__global__ __launch_bounds__(512) void gemm2_rw_kernel(
    int tiles,
    const float* __restrict__ A1, const float* __restrict__ A2,
    const float* __restrict__ A3,
    const short* __restrict__ W1, const short* __restrict__ W2,
    const float* __restrict__ b1, const float* __restrict__ b2,
    const float* __restrict__ aux,
    float* __restrict__ out1, float* __restrict__ out2)
{
  const int t = threadIdx.x, wv = t >> 6, lane = t & 63;
  const int l15 = lane & 15, l4 = lane >> 4;
  constexpr int KS1 = 4, KS = KS1 + KS2;
  bf16x8 W1r[KS], W2r[KS];
  #pragma unroll
  for (int ks = 0; ks < KS; ++ks){
    const size_t fo = ((size_t)(ks * 4 + l4) * 128 + wv * 16 + l15) * 8;
    W1r[ks] = *(const bf16x8*)&W1[fo];
    W2r[ks] = *(const bf16x8*)&W2[fo];
  }

  for (int tile = blockIdx.x; tile < tiles; tile += gridDim.x){
    const int rw = tile * 32;
    f32x4 p10 = {0.f,0.f,0.f,0.f}, p11 = {0.f,0.f,0.f,0.f};
    f32x4 p20 = {0.f,0.f,0.f,0.f}, p21 = {0.f,0.f,0.f,0.f};
    #pragma unroll
    for (int ks = 0; ks < KS1; ++ks){
      const int kl = ks * 32 + l4 * 8;
      const bf16x8 a0 = ldcvt(A1 + (size_t)(rw + l15) * (KS1 * 32) + kl);
      const bf16x8 a1 = ldcvt(A1 + (size_t)(rw + 16 + l15) * (KS1 * 32) + kl);
      p10 = __builtin_amdgcn_mfma_f32_16x16x32_bf16(a0, W1r[ks], p10, 0, 0, 0);
      p20 = __builtin_amdgcn_mfma_f32_16x16x32_bf16(a0, W2r[ks], p20, 0, 0, 0);
      p11 = __builtin_amdgcn_mfma_f32_16x16x32_bf16(a1, W1r[ks], p11, 0, 0, 0);
      p21 = __builtin_amdgcn_mfma_f32_16x16x32_bf16(a1, W2r[ks], p21, 0, 0, 0);
    }
    #pragma unroll
    for (int ks = 0; ks < KS2; ++ks){
      const int kl = ks * 32 + l4 * 8;
      const bf16x8 az0 = ldcvt(A2 + (size_t)(rw + l15) * (KS2 * 32) + kl);
      const bf16x8 az1 = ldcvt(A2 + (size_t)(rw + 16 + l15) * (KS2 * 32) + kl);
      const bf16x8 ah0 = ldcvt(A3 + (size_t)(rw + l15) * (KS2 * 32) + kl);
      const bf16x8 ah1 = ldcvt(A3 + (size_t)(rw + 16 + l15) * (KS2 * 32) + kl);
      p10 = __builtin_amdgcn_mfma_f32_16x16x32_bf16(az0, W1r[KS1 + ks], p10, 0, 0, 0);
      p20 = __builtin_amdgcn_mfma_f32_16x16x32_bf16(ah0, W2r[KS1 + ks], p20, 0, 0, 0);
      p11 = __builtin_amdgcn_mfma_f32_16x16x32_bf16(az1, W1r[KS1 + ks], p11, 0, 0, 0);
      p21 = __builtin_amdgcn_mfma_f32_16x16x32_bf16(ah1, W2r[KS1 + ks], p21, 0, 0, 0);
    }
    const int col = wv * 16 + l15;
    const float bv1 = b1 ? b1[col] : 0.f;
    const float bv2 = b2 ? b2[col] : 0.f;
    #pragma unroll
    for (int rf = 0; rf < 2; ++rf){
      const f32x4 a1c = rf == 0 ? p10 : p11;
      const f32x4 a2c = rf == 0 ? p20 : p21;
      #pragma unroll
      for (int i = 0; i < 4; ++i){
        const int row = rw + rf * 16 + l4 * 4 + i;
        const size_t o = (size_t)row * 128 + col;
        if (MODE == FM_PROJ2){
          out1[o] = a1c[i];
          out2[o] = a2c[i];
        } else {
          const float z = sigmoidf_(a1c[i] + bv1);
          const float h = tanh_fast(a2c[i] + bv2);
          out1[o] = (1.f - z) * aux[o] + z * h;
        }
      }
    }
  }
}

// ---------------- CSR build (by lg_dst) ----------------

__global__ __launch_bounds__(256) void csr_count_kernel(
    const int* __restrict__ lg_dst, int ELG,
    int* __restrict__ cnt, int* __restrict__ ticket)
{
  const int e = blockIdx.x * 256 + threadIdx.x;
  if (e < ELG) ticket[e] = atomicAdd(&cnt[lg_dst[e]], 1);
}

#define SCAN_CHUNK 1024

__global__ __launch_bounds__(256) void scan_totals_kernel(
    const int* __restrict__ cnt, int n, int* __restrict__ bsum)
{
  __shared__ int red[256];
  const int base = blockIdx.x * SCAN_CHUNK;
  const int t = threadIdx.x;
  int s = 0;
  #pragma unroll
  for (int k = 0; k < 4; ++k){
    const int idx = base + t + k * 256;
    if (idx < n) s += cnt[idx];
  }
  red[t] = s; __syncthreads();
  for (int g = 128; g; g >>= 1){
    if (t < g) red[t] += red[t + g];
    __syncthreads();
  }
  if (t == 0) bsum[blockIdx.x] = red[0];
}

__global__ void scan_serial_kernel(int* bsum, int nb, int* offsets, int n)
{
  if (threadIdx.x == 0 && blockIdx.x == 0){
    int acc = 0;
    for (int i = 0; i < nb; ++i){ const int v = bsum[i]; bsum[i] = acc; acc += v; }
    offsets[n] = acc;
  }
}

__global__ __launch_bounds__(256) void scan_write_kernel(
    const int* __restrict__ cnt, int n,
    const int* __restrict__ bsum, int* __restrict__ offsets)
{
  __shared__ int wsum[4];
  const int base = blockIdx.x * SCAN_CHUNK;
  const int t = threadIdx.x;
  int v[4]; int lsum = 0;
  #pragma unroll
  for (int k = 0; k < 4; ++k){
    const int idx = base + t * 4 + k;
    v[k] = (idx < n) ? cnt[idx] : 0;
    lsum += v[k];
  }
  const int lane = t & 63, wv = t >> 6;
  int x = lsum;
  #pragma unroll
  for (int off = 1; off < 64; off <<= 1){
    const int y = __shfl_up(x, off, 64);
    if (lane >= off) x += y;
  }
  if (lane == 63) wsum[wv] = x;
  __syncthreads();
  int woff = 0;
  for (int i = 0; i < wv; ++i) woff += wsum[i];
  int run = x - lsum + woff + bsum[blockIdx.x];
  #pragma unroll
  for (int k = 0; k < 4; ++k){
    const int idx = base + t * 4 + k;
    if (idx < n) offsets[idx] = run;
    run += v[k];
  }
}

__global__ __launch_bounds__(256) void csr_fill_kernel(
    const int* __restrict__ lg_src, const int* __restrict__ lg_dst,
    const int* __restrict__ ticket, int ELG,
    const int* __restrict__ offsets, int* __restrict__ csr_src)
{
  const int e = blockIdx.x * 256 + threadIdx.x;
  if (e >= ELG) return;
  csr_src[offsets[lg_dst[e]] + ticket[e]] = lg_src[e];
}

// ---------------- CSR gathers (one write per dst row) ----------------

__global__ __launch_bounds__(256) void gather2_csr_kernel(
    const int* __restrict__ offsets, const int* __restrict__ csr_src, int E,
    const float* __restrict__ msg, const float* __restrict__ R,
    float* __restrict__ s, float* __restrict__ srh)
{
  const int g = blockIdx.x * 256 + threadIdx.x;
  const int row = g >> 5, q = g & 31;
  if (row >= E) return;
  const int beg = offsets[row], end = offsets[row + 1];
  float4 a = make_float4(0.f, 0.f, 0.f, 0.f);
  float4 c = make_float4(0.f, 0.f, 0.f, 0.f);
  for (int j = beg; j < end; ++j){
    const int si = csr_src[j];
    const float4 m = ((const float4*)msg)[(size_t)si * 32 + q];
    const float4 r = ((const float4*)R)[(size_t)si * 32 + q];
    a.x += m.x; a.y += m.y; a.z += m.z; a.w += m.w;
    c.x += r.x; c.y += r.y; c.z += r.z; c.w += r.w;
  }
  ((float4*)s)[(size_t)row * 32 + q] = a;
  ((float4*)srh)[(size_t)row * 32 + q] = c;
}

__global__ __launch_bounds__(256) void gather1_csr_kernel(
    const int* __restrict__ offsets, const int* __restrict__ csr_src, int E,
    const float* __restrict__ src, float* __restrict__ dst)
{
  const int g = blockIdx.x * 256 + threadIdx.x;
  const int row = g >> 5, q = g & 31;
  if (row >= E) return;
  const int beg = offsets[row], end = offsets[row + 1];
  float4 a = make_float4(0.f, 0.f, 0.f, 0.f);
  for (int j = beg; j < end; ++j){
    const int si = csr_src[j];
    const float4 m = ((const float4*)src)[(size_t)si * 32 + q];
    a.x += m.x; a.y += m.y; a.z += m.z; a.w += m.w;
  }
  ((float4*)dst)[(size_t)row * 32 + q] = a;
}

__global__ __launch_bounds__(256) void gather3_kernel(
    const int* __restrict__ eids, int B,
    const float* __restrict__ f_src, const float* __restrict__ sum_h, const float* __restrict__ msg_new,
    float* __restrict__ fs_e, float* __restrict__ sh_e, float* __restrict__ m_e)
{
  const int g = blockIdx.x * 256 + threadIdx.x;
  const int bI = g >> 5, q = g & 31;
  if (bI >= B) return;
  const int e = eids[bI];
  ((float4*)fs_e)[(size_t)bI * 32 + q] = ((const float4*)f_src)[(size_t)e * 32 + q];
  ((float4*)sh_e)[(size_t)bI * 32 + q] = ((const float4*)sum_h)[(size_t)e * 32 + q];
  ((float4*)m_e )[(size_t)bI * 32 + q] = ((const float4*)msg_new)[(size_t)e * 32 + q];
}

// Per-graph attention over contiguous segments of n nodes; both heads fused.
__global__ __launch_bounds__(64) void attn_kernel(
    const float* __restrict__ x, int n,
    const float* __restrict__ ha_d, const float* __restrict__ ha_l,
    float* __restrict__ out_d, float* __restrict__ out_l,
    int out_stride, int col_off)
{
  const int b = blockIdx.x, l = threadIdx.x;
  __shared__ __align__(16) float hd[128], hl[128];
  __shared__ float pd[64], pl[64];
  hd[l]      = ha_d[(size_t)b * 128 + l];
  hd[l + 64] = ha_d[(size_t)b * 128 + 64 + l];
  hl[l]      = ha_l[(size_t)b * 128 + l];
  hl[l + 64] = ha_l[(size_t)b * 128 + 64 + l];
  __syncthreads();
  float ed = -1e30f, el = -1e30f;
  if (l < n){
    const float4* xr = (const float4*)(x + ((size_t)b * n + l) * 128);
    float sd = 0.f, sl = 0.f;
    #pragma unroll 8
    for (int k = 0; k < 32; ++k){
      const float4 xv = xr[k];
      const float4 hdv = *(const float4*)&hd[k * 4];
      const float4 hlv = *(const float4*)&hl[k * 4];
      sd += xv.x * hdv.x + xv.y * hdv.y + xv.z * hdv.z + xv.w * hdv.w;
      sl += xv.x * hlv.x + xv.y * hlv.y + xv.z * hlv.z + xv.w * hlv.w;
    }
    ed = sd; el = sl;
  }
  const float md = wave_max64(ed), ml = wave_max64(el);
  const float exd = (l < n) ? __expf(ed - md) : 0.f;
  const float exl = (l < n) ? __expf(el - ml) : 0.f;
  const float zd = wave_sum64(exd), zl = wave_sum64(exl);
  pd[l] = exd / zd;
  pl[l] = exl / zl;
  __syncthreads();
  float od0 = 0.f, od1 = 0.f, ol0 = 0.f, ol1 = 0.f;
  for (int i = 0; i < n; ++i){
    const float* xr = x + ((size_t)b * n + i) * 128;
    const float x0 = xr[l], x1 = xr[l + 64];
    const float wd = pd[i], wl = pl[i];
    od0 += wd * x0; od1 += wd * x1;
    ol0 += wl * x0; ol1 += wl * x1;
  }
  const size_t o = (size_t)b * out_stride + col_off;
  out_d[o + l] = od0; out_d[o + 64 + l] = od1;
  out_l[o + l] = ol0; out_l[o + 64 + l] = ol1;
}

__global__ __launch_bounds__(256) void ce_topo_kernel(
    const float* __restrict__ z_d, const float* __restrict__ u_d,
    const float* __restrict__ b_d3, const float* __restrict__ expand,
    float* __restrict__ out, int B)
{
  const int r = blockIdx.x * 4 + (threadIdx.x >> 6);
  const int l = threadIdx.x & 63;
  if (r >= B) return;
  const float* row = z_d + (size_t)r * 128;
  float s = row[l] * u_d[l] + row[l + 64] * u_d[l + 64];
  s = wave_sum64(s);
  if (l == 0){
    const float p = s + b_d3[0];
    const float t = expand[r];
    const float loss = -(t * logsigf_(p) + (1.f - t) * logsigf_(1.f - p));
    atomicAdd(out, loss / (float)B);
  }
}

__global__ __launch_bounds__(256) void ce_label_kernel(
    const float* __restrict__ z_l, const float* __restrict__ u_l,
    const float* __restrict__ b_l2, const int* __restrict__ wid,
    float* __restrict__ out, int B, int V)
{
  const int r = blockIdx.x, t = threadIdx.x;
  __shared__ float zrow[128];
  __shared__ float qs[1024];
  __shared__ float red[256];
  if (t < 128) zrow[t] = z_l[(size_t)r * 128 + t];
  __syncthreads();
  float q[4];
  int nj = 0;
  for (int jj = 0; jj < 4; ++jj){
    const int j = t + jj * 256;
    if (j >= V) break;
    float acc = b_l2[j];
    for (int k = 0; k < 128; ++k) acc += zrow[k] * u_l[(size_t)k * V + j];
    qs[j] = acc; q[jj] = acc; nj = jj + 1;
  }
  float mx = -1e30f;
  for (int jj = 0; jj < nj; ++jj) mx = fmaxf(mx, q[jj]);
  red[t] = mx; __syncthreads();
  for (int sgap = 128; sgap; sgap >>= 1){
    if (t < sgap) red[t] = fmaxf(red[t], red[t + sgap]);
    __syncthreads();
  }
  mx = red[0]; __syncthreads();
  float se = 0.f;
  for (int jj = 0; jj < nj; ++jj) se += __expf(q[jj] - mx);
  red[t] = se; __syncthreads();
  for (int sgap = 128; sgap; sgap >>= 1){
    if (t < sgap) red[t] += red[t + sgap];
    __syncthreads();
  }
  if (t == 0){
    const float lp = qs[wid[r]] - mx - __logf(red[0]);
    atomicAdd(out + 1, -lp / (float)B);
  }
}

extern "C" void kernel_launch(void* const* d_in, const int* in_sizes, int n_in,
                              void* d_out, int out_size, void* d_ws, size_t ws_size,
                              hipStream_t stream)
{
  const float* msg    = (const float*)d_in[0];
  const float* f_src  = (const float*)d_in[1];
  const float* f_dst  = (const float*)d_in[2];
  const float* x_T    = (const float*)d_in[3];
  const float* x_G    = (const float*)d_in[4];
  const float* expand = (const float*)d_in[5];
  const float* wz = (const float*)d_in[6];
  const float* uz = (const float*)d_in[7];
  const float* bz = (const float*)d_in[8];
  const float* wr = (const float*)d_in[9];
  const float* ur = (const float*)d_in[10];
  const float* br = (const float*)d_in[11];
  const float* w  = (const float*)d_in[12];
  const float* u  = (const float*)d_in[13];
  const float* b  = (const float*)d_in[14];
  const float* w_d1 = (const float*)d_in[15];
  const float* w_d2 = (const float*)d_in[16];
  const float* b_d1 = (const float*)d_in[17];
  const float* a_dT = (const float*)d_in[18];
  const float* a_dG = (const float*)d_in[19];
  const float* w_d3 = (const float*)d_in[20];
  const float* w_d4 = (const float*)d_in[21];
  const float* b_d2 = (const float*)d_in[22];
  const float* u_d  = (const float*)d_in[23];
  const float* b_d3 = (const float*)d_in[24];
  const float* w_l1 = (const float*)d_in[25];
  const float* w_l2 = (const float*)d_in[26];
  const float* b_l1 = (const float*)d_in[27];
  const float* a_lT = (const float*)d_in[28];
  const float* a_lG = (const float*)d_in[29];
  const float* u_l  = (const float*)d_in[30];
  const float* b_l2 = (const float*)d_in[31];
  const int* lg_src = (const int*)d_in[32];
  const int* lg_dst = (const int*)d_in[33];
  const int* eids   = (const int*)d_in[34];
  const int* wid    = (const int*)d_in[35];

  const int d = 128;
  const int E   = in_sizes[0] / d;
  const int ELG = in_sizes[32];
  const int B   = in_sizes[34];
  const int V   = in_sizes[31];
  const int nT  = (in_sizes[3] / d) / B;
  const int nG  = (in_sizes[4] / d) / B;

  const size_t EB = (size_t)E * d * sizeof(float);
  const size_t BB = (size_t)B * d * sizeof(float);
  char* p = (char*)d_ws;
  float* buf0 = (float*)p; p += EB;   // R -> msg_new
  float* buf1 = (float*)p; p += EB;   // s
  float* buf2 = (float*)p; p += EB;   // srh -> sum_h
  float* fs_e = (float*)p; p += BB;
  float* sh_e = (float*)p; p += BB;
  float* m_e  = (float*)p; p += BB;
  float* h_t  = (float*)p; p += BB;
  float* haTd = (float*)p; p += BB;
  float* haGd = (float*)p; p += BB;
  float* haTl = (float*)p; p += BB;
  float* haGl = (float*)p; p += BB;
  float* c_d  = (float*)p; p += 2 * BB;
  float* c_l  = (float*)p; p += 2 * BB;
  float* z_d  = (float*)p; p += BB;
  float* z_l  = (float*)p; p += BB;
  // CSR scratch
  int* cnt     = (int*)p; p += (size_t)E * sizeof(int);
  int* offsets = (int*)p; p += (size_t)(E + 1) * sizeof(int);
  int* ticket  = (int*)p; p += (size_t)ELG * sizeof(int);
  int* csr_src = (int*)p; p += (size_t)ELG * sizeof(int);
  int* bsum    = (int*)p; p += (size_t)((E + SCAN_CHUNK - 1) / SCAN_CHUNK + 1) * sizeof(int);
  // bf16 fragment-layout weights
  p = (char*)(((size_t)p + 255) & ~(size_t)255);
  short* wt = (short*)p; p += 294912 * sizeof(short);

  hipMemsetAsync(cnt, 0, (size_t)E * sizeof(int), stream);
  hipMemsetAsync(d_out, 0, 2 * sizeof(float), stream);

  const int nb = (E + SCAN_CHUNK - 1) / SCAN_CHUNK;
  const int GROW = (E * 32 + 255) / 256;
  const int tilesE = E / 32, tilesB = B / 32;
  const int gE1 = tilesE < 2048 ? tilesE : 2048;
  const int gE2 = tilesE < 1024 ? tilesE : 1024;

  // weights -> bf16 fragment layout
  wprep_kernel<<<dim3(24, 10), 256, 0, stream>>>(wr, ur, wz, uz, w, u, w_d1, w_d2,
                                                 a_dT, a_dG, a_lT, a_lG,
                                                 w_d3, w_d4, w_l1, w_l2, wt);

  // ---- CSR build (by lg_dst), reused for both segment sums ----
  csr_count_kernel<<<(ELG + 255) / 256, 256, 0, stream>>>(lg_dst, ELG, cnt, ticket);
  scan_totals_kernel<<<nb, 256, 0, stream>>>(cnt, E, bsum);
  scan_serial_kernel<<<1, 64, 0, stream>>>(bsum, nb, offsets, E);
  scan_write_kernel<<<nb, 256, 0, stream>>>(cnt, E, bsum, offsets);
  csr_fill_kernel<<<(ELG + 255) / 256, 256, 0, stream>>>(lg_src, lg_dst, ticket, ELG, offsets, csr_src);

  // R = sigmoid(f_dst@wr + msg@ur + br) * msg           -> buf0
  gemm_rw_kernel<4, 4, EPI_SIGMUL><<<gE1, 256, 0, stream>>>(
      tilesE, f_dst, msg, wt + 0, br, msg, buf0);
  // s = segsum(msg), srh = segsum(R)                    -> buf1, buf2
  gather2_csr_kernel<<<GROW, 256, 0, stream>>>(offsets, csr_src, E, msg, buf0, buf1, buf2);
  // msg_new = (1-z)*s + z*tanh(...)  (z,h~ fused)       -> buf0
  gemm2_rw_kernel<4, FM_GRUMIX><<<gE2, 512, 0, stream>>>(
      tilesE, f_src, buf1, buf2, wt + 32768, wt + 65536, bz, b, buf1, buf0, nullptr);
  // sum_h = segsum(msg_new)                             -> buf2
  gather1_csr_kernel<<<GROW, 256, 0, stream>>>(offsets, csr_src, E, buf0, buf2);
  // gathers at eids
  gather3_kernel<<<(B * 32 + 255) / 256, 256, 0, stream>>>(eids, B, f_src, buf2, buf0,
                                                           fs_e, sh_e, m_e);
  // h_t = relu(fs_e@w_d1 + sh_e@w_d2 + b_d1)
  gemm_rw_kernel<4, 4, EPI_RELU><<<tilesB, 256, 0, stream>>>(
      tilesB, fs_e, sh_e, wt + 98304, b_d1, nullptr, h_t);
  // attention projections (pairwise, both W in regs)
  gemm2_rw_kernel<0, FM_PROJ2><<<tilesB, 512, 0, stream>>>(
      tilesB, h_t, nullptr, nullptr, wt + 131072, wt + 147456,
      nullptr, nullptr, nullptr, haTd, haGd);
  gemm2_rw_kernel<0, FM_PROJ2><<<tilesB, 512, 0, stream>>>(
      tilesB, m_e, nullptr, nullptr, wt + 163840, wt + 180224,
      nullptr, nullptr, nullptr, haTl, haGl);
  // fused attention (both heads share one pass over x)
  attn_kernel<<<B, 64, 0, stream>>>(x_T, nT, haTd, haTl, c_d, c_l, 2 * d, 0);
  attn_kernel<<<B, 64, 0, stream>>>(x_G, nG, haGd, haGl, c_d, c_l, 2 * d, d);
  // z_d = relu(h_t@w_d3 + c_d@w_d4 + b_d2)
  gemm_rw_kernel<4, 8, EPI_RELU><<<tilesB, 256, 0, stream>>>(
      tilesB, h_t, c_d, wt + 196608, b_d2, nullptr, z_d);
  // z_l = relu(m_e@w_l1 + c_l@w_l2 + b_l1)
  gemm_rw_kernel<4, 8, EPI_RELU><<<tilesB, 256, 0, stream>>>(
      tilesB, m_e, c_l, wt + 245760, b_l1, nullptr, z_l);
  // losses
  ce_topo_kernel<<<(B + 3) / 4, 256, 0, stream>>>(z_d, u_d, b_d3, expand, (float*)d_out, B);
  ce_label_kernel<<<B, 256, 0, stream>>>(z_l, u_l, b_l2, wid, (float*)d_out, B, V);
}

// Round 8
// 984.858 us; speedup vs baseline: 1.1659x; 1.1659x over previous
//
#include <hip/hip_runtime.h>
#include <math.h>

// G2GDecoder forward: TreeGRU over line graph + topology/label heads.
// R2: CSR-gather segment sums. R5: bf16 MFMA.
// R8: (a) W fragments PINNED in VGPRs via empty inline-asm (R7's compiler
// rematerialized them into per-tile L2 loads -> 856 GB/s); (b) all E-path
// data bf16 (one cvt pass; ~25% less HBM traffic; A-loads are single 16B
// dwordx4, no in-loop cvt); (c) per-tile loads batched ahead of the MFMA
// chain for memory-level parallelism.

using bf16x8 = __attribute__((ext_vector_type(8))) short;
using f32x4  = __attribute__((ext_vector_type(4))) float;

#define MFMA __builtin_amdgcn_mfma_f32_16x16x32_bf16

__device__ inline void pinv(bf16x8& v){ asm volatile("" : "+v"(*(f32x4*)&v)); }

__device__ inline float wave_sum64(float v){
  #pragma unroll
  for (int m = 32; m; m >>= 1) v += __shfl_xor(v, m, 64);
  return v;
}
__device__ inline float wave_max64(float v){
  #pragma unroll
  for (int m = 32; m; m >>= 1) v = fmaxf(v, __shfl_xor(v, m, 64));
  return v;
}
__device__ inline float sigmoidf_(float x){ return 1.f / (1.f + __expf(-x)); }
__device__ inline float tanh_fast(float x){
  x = fminf(fmaxf(x, -15.f), 15.f);
  float e = __expf(2.f * x);
  return (e - 1.f) / (e + 1.f);
}
__device__ inline float logsigf_(float x){
  return (x >= 0.f) ? -log1pf(__expf(-x)) : (x - log1pf(__expf(x)));
}
__device__ inline unsigned short f2bf(float f){
  union { float f; unsigned u; } v; v.f = f;
  const unsigned r = v.u + 0x7FFF + ((v.u >> 16) & 1);   // RNE
  return (unsigned short)(r >> 16);
}
__device__ inline float bf2f(unsigned short u){
  union { unsigned u; float f; } v; v.u = ((unsigned)u) << 16; return v.f;
}
__device__ inline unsigned pk2(unsigned short a, unsigned short b){
  return (unsigned)a | ((unsigned)b << 16);
}
__device__ inline void acc8(float* a, uint4 v){
  a[0] += bf2f(v.x & 0xffff); a[1] += bf2f(v.x >> 16);
  a[2] += bf2f(v.y & 0xffff); a[3] += bf2f(v.y >> 16);
  a[4] += bf2f(v.z & 0xffff); a[5] += bf2f(v.z >> 16);
  a[6] += bf2f(v.w & 0xffff); a[7] += bf2f(v.w >> 16);
}
__device__ inline uint4 pack8(const float* a){
  uint4 o;
  o.x = pk2(f2bf(a[0]), f2bf(a[1])); o.y = pk2(f2bf(a[2]), f2bf(a[3]));
  o.z = pk2(f2bf(a[4]), f2bf(a[5])); o.w = pk2(f2bf(a[6]), f2bf(a[7]));
  return o;
}

enum { EPI_NONE = 0, EPI_SIGMOID = 1, EPI_RELU = 2, EPI_SIGMUL = 3 };

// ---------------- weight prep: f32 [k][col] -> bf16 fragment layout ----------
// granule g = k8*128 + col holds 8 bf16 (k = k8*8 .. +7) at wt[off + g*8].
__global__ __launch_bounds__(256) void wprep_kernel(
    const float* wr, const float* ur, const float* wz, const float* uz,
    const float* w,  const float* u,  const float* w_d1, const float* w_d2,
    const float* a_dT, const float* a_dG, const float* a_lT, const float* a_lG,
    const float* w_d3, const float* w_d4, const float* w_l1, const float* w_l2,
    unsigned short* __restrict__ wt)
{
  const int m = blockIdx.y;
  const float* s1; const float* s2; int K1, Ktot; size_t off;
  switch (m){
    case 0: s1 = wr;   s2 = ur;   K1 = 128; Ktot = 256; off = 0;      break;
    case 1: s1 = wz;   s2 = uz;   K1 = 128; Ktot = 256; off = 32768;  break;
    case 2: s1 = w;    s2 = u;    K1 = 128; Ktot = 256; off = 65536;  break;
    case 3: s1 = w_d1; s2 = w_d2; K1 = 128; Ktot = 256; off = 98304;  break;
    case 4: s1 = a_dT; s2 = nullptr; K1 = 128; Ktot = 128; off = 131072; break;
    case 5: s1 = a_dG; s2 = nullptr; K1 = 128; Ktot = 128; off = 147456; break;
    case 6: s1 = a_lT; s2 = nullptr; K1 = 128; Ktot = 128; off = 163840; break;
    case 7: s1 = a_lG; s2 = nullptr; K1 = 128; Ktot = 128; off = 180224; break;
    case 8: s1 = w_d3; s2 = w_d4; K1 = 128; Ktot = 384; off = 196608; break;
    default:s1 = w_l1; s2 = w_l2; K1 = 128; Ktot = 384; off = 245760; break;
  }
  const int tid = blockIdx.x * 256 + threadIdx.x;
  if (tid >= 16 * Ktot) return;
  const int col = tid & 127, k8 = tid >> 7;
  unsigned short v[8];
  #pragma unroll
  for (int i = 0; i < 8; ++i){
    const int k = k8 * 8 + i;
    const float* s = (k < K1) ? (s1 + (size_t)k * 128 + col)
                              : (s2 + (size_t)(k - K1) * 128 + col);
    v[i] = f2bf(*s);
  }
  uint4 pk;
  pk.x = pk2(v[0], v[1]); pk.y = pk2(v[2], v[3]);
  pk.z = pk2(v[4], v[5]); pk.w = pk2(v[6], v[7]);
  *(uint4*)&wt[off + ((size_t)k8 * 128 + col) * 8] = pk;
}

// ---------------- f32 -> bf16 conversion of the three E-matrices ----------
__global__ __launch_bounds__(256) void cvt3_kernel(
    const float* __restrict__ s0, const float* __restrict__ s1, const float* __restrict__ s2,
    unsigned short* __restrict__ d0, unsigned short* __restrict__ d1, unsigned short* __restrict__ d2,
    int n8)
{
  for (int i = blockIdx.x * 256 + threadIdx.x; i < n8; i += gridDim.x * 256){
    #pragma unroll
    for (int a = 0; a < 3; ++a){
      const float* s = a == 0 ? s0 : (a == 1 ? s1 : s2);
      unsigned short* dd = a == 0 ? d0 : (a == 1 ? d1 : d2);
      const float4 x0 = ((const float4*)s)[i * 2];
      const float4 x1 = ((const float4*)s)[i * 2 + 1];
      uint4 o;
      o.x = pk2(f2bf(x0.x), f2bf(x0.y)); o.y = pk2(f2bf(x0.z), f2bf(x0.w));
      o.z = pk2(f2bf(x1.x), f2bf(x1.y)); o.w = pk2(f2bf(x1.z), f2bf(x1.w));
      ((uint4*)dd)[i] = o;
    }
  }
}

// ---------------- bf16-A register-W MFMA GEMM (single mat) ----------------
// out[M,128] = epi( A1[M,KS1*32]@W[0:..] + A2[M,KS2*32]@W[..:] + bias )
// 512 thr = 8 waves, 16 cols/wave, 32 rows/tile; grid-stride over tiles.
template<int KS1, int KS2, int EPI, bool OB16>
__global__ __launch_bounds__(512) void gemm1_kernel(
    int tiles,
    const unsigned short* __restrict__ A1,
    const unsigned short* __restrict__ A2,
    const unsigned short* __restrict__ Wt,
    const float* __restrict__ bias,
    const unsigned short* __restrict__ aux,
    void* __restrict__ outv)
{
  const int t = threadIdx.x, wv = t >> 6, lane = t & 63;
  const int l15 = lane & 15, l4 = lane >> 4;
  constexpr int KS = KS1 + KS2;
  bf16x8 Wr[KS];
  #pragma unroll
  for (int ks = 0; ks < KS; ++ks){
    Wr[ks] = *(const bf16x8*)&Wt[((size_t)(ks * 4 + l4) * 128 + wv * 16 + l15) * 8];
    pinv(Wr[ks]);
  }
  for (int tile = blockIdx.x; tile < tiles; tile += gridDim.x){
    const int rw = tile * 32;
    bf16x8 ar[KS][2];
    #pragma unroll
    for (int ks = 0; ks < KS1; ++ks)
      #pragma unroll
      for (int rf = 0; rf < 2; ++rf)
        ar[ks][rf] = *(const bf16x8*)&A1[(size_t)(rw + rf * 16 + l15) * (KS1 * 32) + ks * 32 + l4 * 8];
    #pragma unroll
    for (int ks = 0; ks < KS2; ++ks)
      #pragma unroll
      for (int rf = 0; rf < 2; ++rf)
        ar[KS1 + ks][rf] = *(const bf16x8*)&A2[(size_t)(rw + rf * 16 + l15) * (KS2 * 32) + ks * 32 + l4 * 8];
    f32x4 acc0 = {0.f,0.f,0.f,0.f}, acc1 = {0.f,0.f,0.f,0.f};
    #pragma unroll
    for (int ks = 0; ks < KS; ++ks){
      acc0 = MFMA(ar[ks][0], Wr[ks], acc0, 0, 0, 0);
      acc1 = MFMA(ar[ks][1], Wr[ks], acc1, 0, 0, 0);
    }
    const int col = wv * 16 + l15;
    const float bv = bias ? bias[col] : 0.f;
    #pragma unroll
    for (int rf = 0; rf < 2; ++rf){
      const f32x4 ac = rf == 0 ? acc0 : acc1;
      #pragma unroll
      for (int i = 0; i < 4; ++i){
        const int row = rw + rf * 16 + l4 * 4 + i;
        const size_t o = (size_t)row * 128 + col;
        float v = ac[i] + bv;
        if (EPI == EPI_RELU)        v = fmaxf(v, 0.f);
        else if (EPI == EPI_SIGMOID) v = sigmoidf_(v);
        else if (EPI == EPI_SIGMUL)  v = sigmoidf_(v) * bf2f(aux[o]);
        if (OB16) ((unsigned short*)outv)[o] = f2bf(v);
        else      ((float*)outv)[o] = v;
      }
    }
  }
}

// ---------------- GRU fused: z & h~ GEMMs + mix epilogue ----------------
// z = sig(A1@W1[0:128] + A2@W1[128:] + b1), h = tanh(A1@W2[0:128] + A3@W2[128:] + b2)
// out = (1-z)*A2 + z*h   (A2 = s16)
__global__ __launch_bounds__(512) void gemm_gru_kernel(
    int tiles,
    const unsigned short* __restrict__ A1, const unsigned short* __restrict__ A2,
    const unsigned short* __restrict__ A3,
    const unsigned short* __restrict__ W1t, const unsigned short* __restrict__ W2t,
    const float* __restrict__ b1, const float* __restrict__ b2,
    unsigned short* __restrict__ out)
{
  const int t = threadIdx.x, wv = t >> 6, lane = t & 63;
  const int l15 = lane & 15, l4 = lane >> 4;
  bf16x8 W1r[8], W2r[8];
  #pragma unroll
  for (int ks = 0; ks < 8; ++ks){
    const size_t fo = ((size_t)(ks * 4 + l4) * 128 + wv * 16 + l15) * 8;
    W1r[ks] = *(const bf16x8*)&W1t[fo]; pinv(W1r[ks]);
    W2r[ks] = *(const bf16x8*)&W2t[fo]; pinv(W2r[ks]);
  }
  for (int tile = blockIdx.x; tile < tiles; tile += gridDim.x){
    const int rw = tile * 32;
    bf16x8 a1[4][2], a2[4][2], a3[4][2];
    #pragma unroll
    for (int ks = 0; ks < 4; ++ks)
      #pragma unroll
      for (int rf = 0; rf < 2; ++rf){
        const size_t ro = (size_t)(rw + rf * 16 + l15) * 128 + ks * 32 + l4 * 8;
        a1[ks][rf] = *(const bf16x8*)&A1[ro];
        a2[ks][rf] = *(const bf16x8*)&A2[ro];
        a3[ks][rf] = *(const bf16x8*)&A3[ro];
      }
    f32x4 az0 = {0.f,0.f,0.f,0.f}, az1 = {0.f,0.f,0.f,0.f};
    f32x4 ah0 = {0.f,0.f,0.f,0.f}, ah1 = {0.f,0.f,0.f,0.f};
    #pragma unroll
    for (int ks = 0; ks < 4; ++ks){
      az0 = MFMA(a1[ks][0], W1r[ks], az0, 0, 0, 0);
      ah0 = MFMA(a1[ks][0], W2r[ks], ah0, 0, 0, 0);
      az1 = MFMA(a1[ks][1], W1r[ks], az1, 0, 0, 0);
      ah1 = MFMA(a1[ks][1], W2r[ks], ah1, 0, 0, 0);
    }
    #pragma unroll
    for (int ks = 0; ks < 4; ++ks){
      az0 = MFMA(a2[ks][0], W1r[4 + ks], az0, 0, 0, 0);
      ah0 = MFMA(a3[ks][0], W2r[4 + ks], ah0, 0, 0, 0);
      az1 = MFMA(a2[ks][1], W1r[4 + ks], az1, 0, 0, 0);
      ah1 = MFMA(a3[ks][1], W2r[4 + ks], ah1, 0, 0, 0);
    }
    const int col = wv * 16 + l15;
    const float bv1 = b1[col], bv2 = b2[col];
    #pragma unroll
    for (int rf = 0; rf < 2; ++rf){
      const f32x4 azc = rf == 0 ? az0 : az1;
      const f32x4 ahc = rf == 0 ? ah0 : ah1;
      #pragma unroll
      for (int i = 0; i < 4; ++i){
        const int row = rw + rf * 16 + l4 * 4 + i;
        const size_t o = (size_t)row * 128 + col;
        const float z = sigmoidf_(azc[i] + bv1);
        const float h = tanh_fast(ahc[i] + bv2);
        out[o] = f2bf((1.f - z) * bf2f(A2[o]) + z * h);
      }
    }
  }
}

// ---------------- projection pair: out1 = A@W1, out2 = A@W2 (K=128) -------
__global__ __launch_bounds__(512) void gemm_proj2_kernel(
    int tiles, const unsigned short* __restrict__ A1,
    const unsigned short* __restrict__ W1t, const unsigned short* __restrict__ W2t,
    float* __restrict__ out1, float* __restrict__ out2)
{
  const int t = threadIdx.x, wv = t >> 6, lane = t & 63;
  const int l15 = lane & 15, l4 = lane >> 4;
  bf16x8 W1r[4], W2r[4];
  #pragma unroll
  for (int ks = 0; ks < 4; ++ks){
    const size_t fo = ((size_t)(ks * 4 + l4) * 128 + wv * 16 + l15) * 8;
    W1r[ks] = *(const bf16x8*)&W1t[fo]; pinv(W1r[ks]);
    W2r[ks] = *(const bf16x8*)&W2t[fo]; pinv(W2r[ks]);
  }
  for (int tile = blockIdx.x; tile < tiles; tile += gridDim.x){
    const int rw = tile * 32;
    bf16x8 a[4][2];
    #pragma unroll
    for (int ks = 0; ks < 4; ++ks)
      #pragma unroll
      for (int rf = 0; rf < 2; ++rf)
        a[ks][rf] = *(const bf16x8*)&A1[(size_t)(rw + rf * 16 + l15) * 128 + ks * 32 + l4 * 8];
    f32x4 p10 = {0.f,0.f,0.f,0.f}, p11 = {0.f,0.f,0.f,0.f};
    f32x4 p20 = {0.f,0.f,0.f,0.f}, p21 = {0.f,0.f,0.f,0.f};
    #pragma unroll
    for (int ks = 0; ks < 4; ++ks){
      p10 = MFMA(a[ks][0], W1r[ks], p10, 0, 0, 0);
      p20 = MFMA(a[ks][0], W2r[ks], p20, 0, 0, 0);
      p11 = MFMA(a[ks][1], W1r[ks], p11, 0, 0, 0);
      p21 = MFMA(a[ks][1], W2r[ks], p21, 0, 0, 0);
    }
    const int col = wv * 16 + l15;
    #pragma unroll
    for (int rf = 0; rf < 2; ++rf){
      const f32x4 c1 = rf == 0 ? p10 : p11;
      const f32x4 c2 = rf == 0 ? p20 : p21;
      #pragma unroll
      for (int i = 0; i < 4; ++i){
        const size_t o = (size_t)(rw + rf * 16 + l4 * 4 + i) * 128 + col;
        out1[o] = c1[i];
        out2[o] = c2[i];
      }
    }
  }
}

// ---------------- CSR build (by lg_dst) ----------------

__global__ __launch_bounds__(256) void csr_count_kernel(
    const int* __restrict__ lg_dst, int ELG,
    int* __restrict__ cnt, int* __restrict__ ticket)
{
  const int e = blockIdx.x * 256 + threadIdx.x;
  if (e < ELG) ticket[e] = atomicAdd(&cnt[lg_dst[e]], 1);
}

#define SCAN_CHUNK 1024

__global__ __launch_bounds__(256) void scan_totals_kernel(
    const int* __restrict__ cnt, int n, int* __restrict__ bsum)
{
  __shared__ int red[256];
  const int base = blockIdx.x * SCAN_CHUNK;
  const int t = threadIdx.x;
  int s = 0;
  #pragma unroll
  for (int k = 0; k < 4; ++k){
    const int idx = base + t + k * 256;
    if (idx < n) s += cnt[idx];
  }
  red[t] = s; __syncthreads();
  for (int g = 128; g; g >>= 1){
    if (t < g) red[t] += red[t + g];
    __syncthreads();
  }
  if (t == 0) bsum[blockIdx.x] = red[0];
}

__global__ void scan_serial_kernel(int* bsum, int nb, int* offsets, int n)
{
  if (threadIdx.x == 0 && blockIdx.x == 0){
    int acc = 0;
    for (int i = 0; i < nb; ++i){ const int v = bsum[i]; bsum[i] = acc; acc += v; }
    offsets[n] = acc;
  }
}

__global__ __launch_bounds__(256) void scan_write_kernel(
    const int* __restrict__ cnt, int n,
    const int* __restrict__ bsum, int* __restrict__ offsets)
{
  __shared__ int wsum[4];
  const int base = blockIdx.x * SCAN_CHUNK;
  const int t = threadIdx.x;
  int v[4]; int lsum = 0;
  #pragma unroll
  for (int k = 0; k < 4; ++k){
    const int idx = base + t * 4 + k;
    v[k] = (idx < n) ? cnt[idx] : 0;
    lsum += v[k];
  }
  const int lane = t & 63, wv = t >> 6;
  int x = lsum;
  #pragma unroll
  for (int off = 1; off < 64; off <<= 1){
    const int y = __shfl_up(x, off, 64);
    if (lane >= off) x += y;
  }
  if (lane == 63) wsum[wv] = x;
  __syncthreads();
  int woff = 0;
  for (int i = 0; i < wv; ++i) woff += wsum[i];
  int run = x - lsum + woff + bsum[blockIdx.x];
  #pragma unroll
  for (int k = 0; k < 4; ++k){
    const int idx = base + t * 4 + k;
    if (idx < n) offsets[idx] = run;
    run += v[k];
  }
}

__global__ __launch_bounds__(256) void csr_fill_kernel(
    const int* __restrict__ lg_src, const int* __restrict__ lg_dst,
    const int* __restrict__ ticket, int ELG,
    const int* __restrict__ offsets, int* __restrict__ csr_src)
{
  const int e = blockIdx.x * 256 + threadIdx.x;
  if (e >= ELG) return;
  csr_src[offsets[lg_dst[e]] + ticket[e]] = lg_src[e];
}

// ---------------- CSR gathers (bf16 rows, f32 accumulate) ----------------

__global__ __launch_bounds__(256) void gather2_bf_kernel(
    const int* __restrict__ offsets, const int* __restrict__ csr_src, int E,
    const unsigned short* __restrict__ msg16, const unsigned short* __restrict__ R16,
    unsigned short* __restrict__ s16, unsigned short* __restrict__ srh16)
{
  const int g = blockIdx.x * 256 + threadIdx.x;
  const int row = g >> 4, q = g & 15;
  if (row >= E) return;
  const int beg = offsets[row], end = offsets[row + 1];
  float as[8] = {}, ar[8] = {};
  for (int j = beg; j < end; ++j){
    const int si = csr_src[j];
    acc8(as, *(const uint4*)&msg16[(size_t)si * 128 + q * 8]);
    acc8(ar, *(const uint4*)&R16[(size_t)si * 128 + q * 8]);
  }
  *(uint4*)&s16[(size_t)row * 128 + q * 8] = pack8(as);
  *(uint4*)&srh16[(size_t)row * 128 + q * 8] = pack8(ar);
}

__global__ __launch_bounds__(256) void gather1_bf_kernel(
    const int* __restrict__ offsets, const int* __restrict__ csr_src, int E,
    const unsigned short* __restrict__ src, unsigned short* __restrict__ dst)
{
  const int g = blockIdx.x * 256 + threadIdx.x;
  const int row = g >> 4, q = g & 15;
  if (row >= E) return;
  const int beg = offsets[row], end = offsets[row + 1];
  float a[8] = {};
  for (int j = beg; j < end; ++j){
    const int si = csr_src[j];
    acc8(a, *(const uint4*)&src[(size_t)si * 128 + q * 8]);
  }
  *(uint4*)&dst[(size_t)row * 128 + q * 8] = pack8(a);
}

__global__ __launch_bounds__(256) void gather3_bf_kernel(
    const int* __restrict__ eids, int B,
    const unsigned short* __restrict__ fs16, const unsigned short* __restrict__ sumh16,
    const unsigned short* __restrict__ mn16,
    unsigned short* __restrict__ fs_e, unsigned short* __restrict__ sh_e,
    unsigned short* __restrict__ m_e)
{
  const int g = blockIdx.x * 256 + threadIdx.x;
  const int bI = g >> 4, q = g & 15;
  if (bI >= B) return;
  const int e = eids[bI];
  *(uint4*)&fs_e[(size_t)bI * 128 + q * 8] = *(const uint4*)&fs16[(size_t)e * 128 + q * 8];
  *(uint4*)&sh_e[(size_t)bI * 128 + q * 8] = *(const uint4*)&sumh16[(size_t)e * 128 + q * 8];
  *(uint4*)&m_e [(size_t)bI * 128 + q * 8] = *(const uint4*)&mn16[(size_t)e * 128 + q * 8];
}

// Per-graph attention over contiguous segments; both heads fused; bf16 c-out.
__global__ __launch_bounds__(64) void attn_kernel(
    const float* __restrict__ x, int n,
    const float* __restrict__ ha_d, const float* __restrict__ ha_l,
    unsigned short* __restrict__ out_d, unsigned short* __restrict__ out_l,
    int out_stride, int col_off)
{
  const int b = blockIdx.x, l = threadIdx.x;
  __shared__ __align__(16) float hd[128], hl[128];
  __shared__ float pd[64], pl[64];
  hd[l]      = ha_d[(size_t)b * 128 + l];
  hd[l + 64] = ha_d[(size_t)b * 128 + 64 + l];
  hl[l]      = ha_l[(size_t)b * 128 + l];
  hl[l + 64] = ha_l[(size_t)b * 128 + 64 + l];
  __syncthreads();
  float ed = -1e30f, el = -1e30f;
  if (l < n){
    const float4* xr = (const float4*)(x + ((size_t)b * n + l) * 128);
    float sd = 0.f, sl = 0.f;
    #pragma unroll 8
    for (int k = 0; k < 32; ++k){
      const float4 xv = xr[k];
      const float4 hdv = *(const float4*)&hd[k * 4];
      const float4 hlv = *(const float4*)&hl[k * 4];
      sd += xv.x * hdv.x + xv.y * hdv.y + xv.z * hdv.z + xv.w * hdv.w;
      sl += xv.x * hlv.x + xv.y * hlv.y + xv.z * hlv.z + xv.w * hlv.w;
    }
    ed = sd; el = sl;
  }
  const float md = wave_max64(ed), ml = wave_max64(el);
  const float exd = (l < n) ? __expf(ed - md) : 0.f;
  const float exl = (l < n) ? __expf(el - ml) : 0.f;
  const float zd = wave_sum64(exd), zl = wave_sum64(exl);
  pd[l] = exd / zd;
  pl[l] = exl / zl;
  __syncthreads();
  float od0 = 0.f, od1 = 0.f, ol0 = 0.f, ol1 = 0.f;
  for (int i = 0; i < n; ++i){
    const float* xr = x + ((size_t)b * n + i) * 128;
    const float x0 = xr[l], x1 = xr[l + 64];
    const float wd = pd[i], wl = pl[i];
    od0 += wd * x0; od1 += wd * x1;
    ol0 += wl * x0; ol1 += wl * x1;
  }
  const size_t o = (size_t)b * out_stride + col_off;
  out_d[o + l] = f2bf(od0); out_d[o + 64 + l] = f2bf(od1);
  out_l[o + l] = f2bf(ol0); out_l[o + 64 + l] = f2bf(ol1);
}

__global__ __launch_bounds__(256) void ce_topo_kernel(
    const float* __restrict__ z_d, const float* __restrict__ u_d,
    const float* __restrict__ b_d3, const float* __restrict__ expand,
    float* __restrict__ out, int B)
{
  const int r = blockIdx.x * 4 + (threadIdx.x >> 6);
  const int l = threadIdx.x & 63;
  if (r >= B) return;
  const float* row = z_d + (size_t)r * 128;
  float s = row[l] * u_d[l] + row[l + 64] * u_d[l + 64];
  s = wave_sum64(s);
  if (l == 0){
    const float p = s + b_d3[0];
    const float t = expand[r];
    const float loss = -(t * logsigf_(p) + (1.f - t) * logsigf_(1.f - p));
    atomicAdd(out, loss / (float)B);
  }
}

__global__ __launch_bounds__(256) void ce_label_kernel(
    const float* __restrict__ z_l, const float* __restrict__ u_l,
    const float* __restrict__ b_l2, const int* __restrict__ wid,
    float* __restrict__ out, int B, int V)
{
  const int r = blockIdx.x, t = threadIdx.x;
  __shared__ float zrow[128];
  __shared__ float qs[1024];
  __shared__ float red[256];
  if (t < 128) zrow[t] = z_l[(size_t)r * 128 + t];
  __syncthreads();
  float q[4];
  int nj = 0;
  for (int jj = 0; jj < 4; ++jj){
    const int j = t + jj * 256;
    if (j >= V) break;
    float acc = b_l2[j];
    for (int k = 0; k < 128; ++k) acc += zrow[k] * u_l[(size_t)k * V + j];
    qs[j] = acc; q[jj] = acc; nj = jj + 1;
  }
  float mx = -1e30f;
  for (int jj = 0; jj < nj; ++jj) mx = fmaxf(mx, q[jj]);
  red[t] = mx; __syncthreads();
  for (int sgap = 128; sgap; sgap >>= 1){
    if (t < sgap) red[t] = fmaxf(red[t], red[t + sgap]);
    __syncthreads();
  }
  mx = red[0]; __syncthreads();
  float se = 0.f;
  for (int jj = 0; jj < nj; ++jj) se += __expf(q[jj] - mx);
  red[t] = se; __syncthreads();
  for (int sgap = 128; sgap; sgap >>= 1){
    if (t < sgap) red[t] += red[t + sgap];
    __syncthreads();
  }
  if (t == 0){
    const float lp = qs[wid[r]] - mx - __logf(red[0]);
    atomicAdd(out + 1, -lp / (float)B);
  }
}

extern "C" void kernel_launch(void* const* d_in, const int* in_sizes, int n_in,
                              void* d_out, int out_size, void* d_ws, size_t ws_size,
                              hipStream_t stream)
{
  const float* msg    = (const float*)d_in[0];
  const float* f_src  = (const float*)d_in[1];
  const float* f_dst  = (const float*)d_in[2];
  const float* x_T    = (const float*)d_in[3];
  const float* x_G    = (const float*)d_in[4];
  const float* expand = (const float*)d_in[5];
  const float* wz = (const float*)d_in[6];
  const float* uz = (const float*)d_in[7];
  const float* bz = (const float*)d_in[8];
  const float* wr = (const float*)d_in[9];
  const float* ur = (const float*)d_in[10];
  const float* br = (const float*)d_in[11];
  const float* w  = (const float*)d_in[12];
  const float* u  = (const float*)d_in[13];
  const float* b  = (const float*)d_in[14];
  const float* w_d1 = (const float*)d_in[15];
  const float* w_d2 = (const float*)d_in[16];
  const float* b_d1 = (const float*)d_in[17];
  const float* a_dT = (const float*)d_in[18];
  const float* a_dG = (const float*)d_in[19];
  const float* w_d3 = (const float*)d_in[20];
  const float* w_d4 = (const float*)d_in[21];
  const float* b_d2 = (const float*)d_in[22];
  const float* u_d  = (const float*)d_in[23];
  const float* b_d3 = (const float*)d_in[24];
  const float* w_l1 = (const float*)d_in[25];
  const float* w_l2 = (const float*)d_in[26];
  const float* b_l1 = (const float*)d_in[27];
  const float* a_lT = (const float*)d_in[28];
  const float* a_lG = (const float*)d_in[29];
  const float* u_l  = (const float*)d_in[30];
  const float* b_l2 = (const float*)d_in[31];
  const int* lg_src = (const int*)d_in[32];
  const int* lg_dst = (const int*)d_in[33];
  const int* eids   = (const int*)d_in[34];
  const int* wid    = (const int*)d_in[35];

  const int d = 128;
  const int E   = in_sizes[0] / d;
  const int ELG = in_sizes[32];
  const int B   = in_sizes[34];
  const int V   = in_sizes[31];
  const int nT  = (in_sizes[3] / d) / B;
  const int nG  = (in_sizes[4] / d) / B;

  const size_t EH = (size_t)E * d * sizeof(unsigned short);   // bf16 E-matrix
  const size_t BH = (size_t)B * d * sizeof(unsigned short);
  const size_t BF = (size_t)B * d * sizeof(float);
  char* p = (char*)d_ws;
  unsigned short* msg16 = (unsigned short*)p; p += EH;
  unsigned short* fs16  = (unsigned short*)p; p += EH;
  unsigned short* fd16  = (unsigned short*)p; p += EH;   // -> msg_new after GRU
  unsigned short* R16   = (unsigned short*)p; p += EH;   // -> sum_h after gather1
  unsigned short* s16   = (unsigned short*)p; p += EH;
  unsigned short* srh16 = (unsigned short*)p; p += EH;
  unsigned short* mn16   = fd16;
  unsigned short* sumh16 = R16;
  unsigned short* fse16 = (unsigned short*)p; p += BH;
  unsigned short* she16 = (unsigned short*)p; p += BH;
  unsigned short* me16  = (unsigned short*)p; p += BH;
  unsigned short* ht16  = (unsigned short*)p; p += BH;
  unsigned short* cd16  = (unsigned short*)p; p += 2 * BH;
  unsigned short* cl16  = (unsigned short*)p; p += 2 * BH;
  float* haTd = (float*)p; p += BF;
  float* haGd = (float*)p; p += BF;
  float* haTl = (float*)p; p += BF;
  float* haGl = (float*)p; p += BF;
  float* z_d  = (float*)p; p += BF;
  float* z_l  = (float*)p; p += BF;
  // CSR scratch
  int* cnt     = (int*)p; p += (size_t)E * sizeof(int);
  int* offsets = (int*)p; p += (size_t)(E + 1) * sizeof(int);
  int* ticket  = (int*)p; p += (size_t)ELG * sizeof(int);
  int* csr_src = (int*)p; p += (size_t)ELG * sizeof(int);
  int* bsum    = (int*)p; p += (size_t)((E + SCAN_CHUNK - 1) / SCAN_CHUNK + 1) * sizeof(int);
  // bf16 fragment-layout weights
  p = (char*)(((size_t)p + 255) & ~(size_t)255);
  unsigned short* wt = (unsigned short*)p; p += 294912 * sizeof(unsigned short);

  hipMemsetAsync(cnt, 0, (size_t)E * sizeof(int), stream);
  hipMemsetAsync(d_out, 0, 2 * sizeof(float), stream);

  const int nb = (E + SCAN_CHUNK - 1) / SCAN_CHUNK;
  const int tilesE = E / 32, tilesB = B / 32;
  const int gE = tilesE < 1984 ? tilesE : 1984;

  // weights -> bf16 fragment layout
  wprep_kernel<<<dim3(24, 10), 256, 0, stream>>>(wr, ur, wz, uz, w, u, w_d1, w_d2,
                                                 a_dT, a_dG, a_lT, a_lG,
                                                 w_d3, w_d4, w_l1, w_l2, wt);
  // E-inputs -> bf16
  cvt3_kernel<<<2048, 256, 0, stream>>>(msg, f_src, f_dst, msg16, fs16, fd16, E * 16);

  // ---- CSR build (by lg_dst), reused for both segment sums ----
  csr_count_kernel<<<(ELG + 255) / 256, 256, 0, stream>>>(lg_dst, ELG, cnt, ticket);
  scan_totals_kernel<<<nb, 256, 0, stream>>>(cnt, E, bsum);
  scan_serial_kernel<<<1, 64, 0, stream>>>(bsum, nb, offsets, E);
  scan_write_kernel<<<nb, 256, 0, stream>>>(cnt, E, bsum, offsets);
  csr_fill_kernel<<<(ELG + 255) / 256, 256, 0, stream>>>(lg_src, lg_dst, ticket, ELG, offsets, csr_src);

  // R = sigmoid(f_dst@wr + msg@ur + br) * msg           -> R16
  gemm1_kernel<4, 4, EPI_SIGMUL, true><<<gE, 512, 0, stream>>>(
      tilesE, fd16, msg16, wt + 0, br, msg16, R16);
  // s = segsum(msg), srh = segsum(R)                    -> s16, srh16
  gather2_bf_kernel<<<(E * 16 + 255) / 256, 256, 0, stream>>>(
      offsets, csr_src, E, msg16, R16, s16, srh16);
  // msg_new = (1-z)*s + z*tanh(...)                     -> mn16 (=fd16)
  gemm_gru_kernel<<<gE, 512, 0, stream>>>(
      tilesE, fs16, s16, srh16, wt + 32768, wt + 65536, bz, b, mn16);
  // sum_h = segsum(msg_new)                             -> sumh16 (=R16)
  gather1_bf_kernel<<<(E * 16 + 255) / 256, 256, 0, stream>>>(
      offsets, csr_src, E, mn16, sumh16);
  // gathers at eids
  gather3_bf_kernel<<<(B * 16 + 255) / 256, 256, 0, stream>>>(
      eids, B, fs16, sumh16, mn16, fse16, she16, me16);
  // h_t = relu(fs_e@w_d1 + sh_e@w_d2 + b_d1)            -> ht16
  gemm1_kernel<4, 4, EPI_RELU, true><<<tilesB, 512, 0, stream>>>(
      tilesB, fse16, she16, wt + 98304, b_d1, nullptr, ht16);
  // attention projections
  gemm_proj2_kernel<<<tilesB, 512, 0, stream>>>(
      tilesB, ht16, wt + 131072, wt + 147456, haTd, haGd);
  gemm_proj2_kernel<<<tilesB, 512, 0, stream>>>(
      tilesB, me16, wt + 163840, wt + 180224, haTl, haGl);
  // fused attention (both heads share one pass over x)
  attn_kernel<<<B, 64, 0, stream>>>(x_T, nT, haTd, haTl, cd16, cl16, 2 * d, 0);
  attn_kernel<<<B, 64, 0, stream>>>(x_G, nG, haGd, haGl, cd16, cl16, 2 * d, d);
  // z_d = relu(h_t@w_d3 + c_d@w_d4 + b_d2)
  gemm1_kernel<4, 8, EPI_RELU, false><<<tilesB, 512, 0, stream>>>(
      tilesB, ht16, cd16, wt + 196608, b_d2, nullptr, z_d);
  // z_l = relu(m_e@w_l1 + c_l@w_l2 + b_l1)
  gemm1_kernel<4, 8, EPI_RELU, false><<<tilesB, 512, 0, stream>>>(
      tilesB, me16, cl16, wt + 245760, b_l1, nullptr, z_l);
  // losses
  ce_topo_kernel<<<(B + 3) / 4, 256, 0, stream>>>(z_d, u_d, b_d3, expand, (float*)d_out, B);
  ce_label_kernel<<<B, 256, 0, stream>>>(z_l, u_l, b_l2, wid, (float*)d_out, B, V);
}